// Round 4
// baseline (260.774 us; speedup 1.0000x reference)
//
#include <hip/hip_runtime.h>
#include <cstdint>
#include <cstddef>

// Low-rank bilinear attention, MI355X/gfx950.
// out = softmax((x@W1)(W2@x^T)/sqrt(512)) @ x,  x:[16,2048,512] fp32.
// kw:  W1/W2 -> B-fragment-ordered f16 table in ws (W1 pre-scaled by 1/sqrt(512)*log2e).
// K01: read x once -> xT f16 [b][d][c] + left fp32 + rightT f16 (factor MFMAs).
// K3:  fused P-recompute (MFMA) + row-sum softmax + (P@x) MFMA GEMM, 128x128, BK=64.

typedef float    f32x4 __attribute__((ext_vector_type(4)));
typedef _Float16 half8 __attribute__((ext_vector_type(8)));

#define B_  16
#define A_  2048
#define D_  512
#define KSCALE 0.06375872f   // (1/sqrt(512)) * log2(e)

__device__ inline float fast_exp2(float v) {
#if __has_builtin(__builtin_amdgcn_exp2f)
    return __builtin_amdgcn_exp2f(v);
#else
    return __expf(v * 0.6931471805599453f);
#endif
}

// ---- kw: build Wf[kt(16)][lane(64)][2 factors][half8]  (32 KB, L2-resident) ----
__global__ __launch_bounds__(256) void kw_prep(const float* __restrict__ W1,
                                               const float* __restrict__ W2,
                                               _Float16* __restrict__ Wf) {
    int pi = blockIdx.x * 256 + threadIdx.x;   // (kt, lane) pair, 1024 total
    int kt = pi >> 6, lane = pi & 63;
    int quad = lane >> 4, col = lane & 15;
    half8 h1, h2;
#pragma unroll
    for (int j = 0; j < 8; ++j) {
        int d = kt * 32 + quad * 8 + j;
        h1[j] = (col < 10) ? (_Float16)(W1[d * 10 + col] * KSCALE) : (_Float16)0.f;
        h2[j] = (col < 12) ? (_Float16)W2[col * 512 + d] : (_Float16)0.f;
    }
    *(half8*)(Wf + (size_t)pi * 16) = h1;
    *(half8*)(Wf + (size_t)pi * 16 + 8) = h2;
}

// ---------------- K01: transpose + factors, x read once ----------------
// Block = 32 a-rows x full D (8 chunks of 64 d). Grid 1024 -> 4 blocks/CU.
// xs swizzle: (c, ch=d>>2, e) at xs[c*64 + ((ch^(c&15))<<2)+e].
// Waves (0,1)->a-tile 0, (2,3)->tile 1; wave pair splits K (kki = w&1).
__global__ __launch_bounds__(256) void k01_prep(const float* __restrict__ x,
                                                const _Float16* __restrict__ Wf,
                                                _Float16* __restrict__ xT,
                                                float* __restrict__ left,
                                                _Float16* __restrict__ rightT) {
    __shared__ float xs[32 * 64];
    int t = threadIdx.x, lane = t & 63, w = t >> 6;
    int quad = lane >> 4, c16 = lane & 15;
    int bid = blockIdx.x;
    int b = bid >> 6, grp = bid & 63;
    int c0 = grp << 5;
    const float* xb = x + ((size_t)b * A_ + c0) * D_;
    int tile = w >> 1, kki = w & 1;
    int ar = tile * 16 + c16;                 // xs row for A-frag (ar&15 == c16)
    f32x4 accA = {0.f, 0.f, 0.f, 0.f}, accB = {0.f, 0.f, 0.f, 0.f};

    for (int dc = 0; dc < 8; ++dc) {
        __syncthreads();
#pragma unroll
        for (int p = 0; p < 2; ++p) {         // load 32c x 64d fp32
            int c = p * 16 + (t >> 4), ch = t & 15;
            float4 v = *(const float4*)(xb + (size_t)c * D_ + dc * 64 + ch * 4);
            *(float4*)&xs[c * 64 + ((ch ^ (c & 15)) << 2)] = v;
        }
        __syncthreads();
        {                                     // transpose out: half8 per thread
            int dloc = t >> 2, c8 = (t & 3) << 3;
            int ch = dloc >> 2, e = dloc & 3;
            half8 h;
#pragma unroll
            for (int j = 0; j < 8; ++j) {
                int c = c8 + j;
                h[j] = (_Float16)xs[c * 64 + ((ch ^ (c & 15)) << 2) + e];
            }
            *(half8*)(xT + ((size_t)b * D_ + dc * 64 + dloc) * A_ + c0 + c8) = h;
        }
        {                                     // factor MFMAs
            int kk = kki * 32;
            int ch0 = (kk >> 2) + quad * 2;
            float4 v0 = *(const float4*)&xs[ar * 64 + ((ch0 ^ c16) << 2)];
            float4 v1 = *(const float4*)&xs[ar * 64 + (((ch0 + 1) ^ c16) << 2)];
            half8 af;
            af[0] = (_Float16)v0.x; af[1] = (_Float16)v0.y; af[2] = (_Float16)v0.z; af[3] = (_Float16)v0.w;
            af[4] = (_Float16)v1.x; af[5] = (_Float16)v1.y; af[6] = (_Float16)v1.z; af[7] = (_Float16)v1.w;
            const half8* wf = (const half8*)(Wf + ((size_t)((dc * 2 + kki) * 64 + lane)) * 16);
            half8 b1 = wf[0], b2 = wf[1];
            accA = __builtin_amdgcn_mfma_f32_16x16x32_f16(af, b1, accA, 0, 0, 0);
            accB = __builtin_amdgcn_mfma_f32_16x16x32_f16(af, b2, accB, 0, 0, 0);
        }
    }
    __syncthreads();
    float* red = xs;                           // reuse: [tile][factor][row16][col16]
    if (kki == 0) {
#pragma unroll
        for (int q = 0; q < 4; ++q) {
            red[tile * 512 + (quad * 4 + q) * 16 + c16] = accA[q];
            red[tile * 512 + 256 + (quad * 4 + q) * 16 + c16] = accB[q];
        }
    }
    __syncthreads();
    if (kki == 1) {
#pragma unroll
        for (int q = 0; q < 4; ++q) {
            float a = accA[q] + red[tile * 512 + (quad * 4 + q) * 16 + c16];
            float bb = accB[q] + red[tile * 512 + 256 + (quad * 4 + q) * 16 + c16];
            size_t grow = (size_t)bid * 32 + tile * 16 + quad * 4 + q;
            if (c16 < 10) left[grow * 10 + c16] = a;
            if (c16 < 12) rightT[grow * 12 + c16] = (_Float16)bb;
        }
    }
}

// ------------- K3: fused P recompute + softmax denom + (P@x) MFMA GEMM -------------
// Block: 128a x 128d, 4 waves (wave = 64a x 64d), BK=64 (32 iters), 3 barriers/iter.
// Grid 1024, XCD-swizzled so a-tiles sharing an xT slab share an XCD L2.
__global__ __launch_bounds__(256, 3) void k3_attn(const _Float16* __restrict__ xT,
                                                  const float* __restrict__ left,
                                                  const _Float16* __restrict__ rightT,
                                                  float* __restrict__ out) {
    __shared__ _Float16 XTl[128][64];    // [d-local][c], rows 128B, 16B-chunk XOR swizzle
    __shared__ _Float16 Ps[2][128][40];  // [c-group][a-local][c-in-group padded]
    __shared__ _Float16 rl[64][40];      // [c-local][r padded to 32]
    __shared__ float rowsum[128];
    int t = threadIdx.x, lane = t & 63, w = t >> 6;
    int quad = lane >> 4, c16 = lane & 15;
    int bid = blockIdx.x;
    // decode: combo = (b,nb) pinned to XCD bid&7; a-tile in bits 3..6
    int combo = (bid & 7) | (((bid >> 7) & 7) << 3);
    int at = (bid >> 3) & 15;
    int b = combo >> 2, nb = combo & 3;
    int a0 = at << 7, n0 = nb << 7;
    int waveM = w & 1, waveN = w >> 1;

    // zero rl pad (r in [12,40) halfs = bytes [24,80)) once
    for (int i = t; i < 896; i += 256) {
        int c = i / 14, dw = i % 14;
        *(uint32_t*)((char*)rl + c * 80 + 24 + dw * 4) = 0u;
    }

    // left A-frags (KSCALE/log2e folded): wave w owns P a-tiles 2w, 2w+1
    half8 lf[2];
#pragma unroll
    for (int i = 0; i < 2; ++i) {
        int arow = a0 + (2 * w + i) * 16 + c16;
        const float* lp = left + (size_t)((b << 11) + arow) * 10;
#pragma unroll
        for (int j = 0; j < 8; ++j) {
            int r = quad * 8 + j;
            lf[i][j] = (r < 10) ? (_Float16)lp[r] : (_Float16)0.f;
        }
    }

    f32x4 acc[4][4];
#pragma unroll
    for (int mi = 0; mi < 4; ++mi)
#pragma unroll
        for (int ni = 0; ni < 4; ++ni) acc[mi][ni] = (f32x4){0.f, 0.f, 0.f, 0.f};
    float psum[2][4] = {{0.f, 0.f, 0.f, 0.f}, {0.f, 0.f, 0.f, 0.f}};

    const _Float16* xTb = xT + ((size_t)b * D_ + n0) * A_;
    const _Float16* rTb = rightT + (size_t)(b << 11) * 12;

    int dmarow = w * 32 + (lane >> 3);   // +cc*8; 8 rows per DMA instr
    int kq = lane & 7;

    for (int kt = 0; kt < 32; ++kt) {
        int c0 = kt << 6;
        __syncthreads();
        // stage rightT tile: 64 rows x 6 dwords
        for (int i = t; i < 384; i += 256) {
            int c = i / 6, dw = i % 6;
            uint32_t v = *(const uint32_t*)((const char*)(rTb + (size_t)(c0 + c) * 12) + dw * 4);
            *(uint32_t*)((char*)rl + c * 80 + dw * 4) = v;
        }
        // DMA XT tile: 128 rows x 128B, 4 instrs/wave, swizzle on src side
#pragma unroll
        for (int cc = 0; cc < 4; ++cc) {
            int nl = dmarow + cc * 8;
            const _Float16* src = xTb + (size_t)nl * A_ + c0 + ((kq ^ (nl & 7)) << 3);
            _Float16* dst = &XTl[w * 32 + cc * 8][0];
            __builtin_amdgcn_global_load_lds((const __attribute__((address_space(1))) void*)src,
                                             (__attribute__((address_space(3))) void*)dst,
                                             16, 0, 0);
        }
        __syncthreads();
        // P phase: 2 c-groups x 2 n-halves x 2 a-tiles = 8 MFMAs/wave
#pragma unroll
        for (int g = 0; g < 2; ++g) {
#pragma unroll
            for (int nh = 0; nh < 2; ++nh) {
                half8 bfr = *(const half8*)((const char*)&rl[g * 32 + nh * 16 + c16][0] + quad * 16);
#pragma unroll
                for (int i = 0; i < 2; ++i) {
                    f32x4 z = {0.f, 0.f, 0.f, 0.f};
                    f32x4 pc = __builtin_amdgcn_mfma_f32_16x16x32_f16(lf[i], bfr, z, 0, 0, 0);
#pragma unroll
                    for (int q = 0; q < 4; ++q) {
                        float p = fast_exp2(pc[q]);
                        psum[i][q] += p;
                        Ps[g][(2 * w + i) * 16 + quad * 4 + q][nh * 16 + c16] = (_Float16)p;
                    }
                }
            }
        }
        __syncthreads();
        // main GEMM: 2 k-halves x 16 MFMAs
#pragma unroll
        for (int g = 0; g < 2; ++g) {
            half8 af[4], bf[4];
#pragma unroll
            for (int mi = 0; mi < 4; ++mi)
                af[mi] = *(const half8*)&Ps[g][waveM * 64 + mi * 16 + c16][quad * 8];
#pragma unroll
            for (int ni = 0; ni < 4; ++ni) {
                int nr = waveN * 64 + ni * 16 + c16;
                bf[ni] = *(const half8*)&XTl[nr][(((g << 2) + quad) ^ (nr & 7)) << 3];
            }
#pragma unroll
            for (int mi = 0; mi < 4; ++mi)
#pragma unroll
                for (int ni = 0; ni < 4; ++ni)
                    acc[mi][ni] = __builtin_amdgcn_mfma_f32_16x16x32_f16(af[mi], bf[ni], acc[mi][ni], 0, 0, 0);
        }
    }

    // softmax denominators: reduce psum over the 16 column lanes
#pragma unroll
    for (int i = 0; i < 2; ++i)
#pragma unroll
        for (int q = 0; q < 4; ++q) {
            float s = psum[i][q];
            s += __shfl_xor(s, 1);
            s += __shfl_xor(s, 2);
            s += __shfl_xor(s, 4);
            s += __shfl_xor(s, 8);
            if (c16 == 0) rowsum[(2 * w + i) * 16 + quad * 4 + q] = s;
        }
    __syncthreads();

    float* ob = out + ((size_t)b * A_ + a0) * D_ + n0;
#pragma unroll
    for (int mi = 0; mi < 4; ++mi) {
#pragma unroll
        for (int q = 0; q < 4; ++q) {
            int ar = waveM * 64 + mi * 16 + quad * 4 + q;
            float sc = 1.0f / rowsum[ar];
#pragma unroll
            for (int ni = 0; ni < 4; ++ni)
                ob[(size_t)ar * D_ + waveN * 64 + ni * 16 + c16] = acc[mi][ni][q] * sc;
        }
    }
}

extern "C" void kernel_launch(void* const* d_in, const int* in_sizes, int n_in,
                              void* d_out, int out_size, void* d_ws, size_t ws_size,
                              hipStream_t stream) {
    const float* x  = (const float*)d_in[0];
    const float* W1 = (const float*)d_in[1];
    const float* W2 = (const float*)d_in[2];
    float* out = (float*)d_out;
    char* ws = (char*)d_ws;
    // ws layout (bytes): xT f16 [16][512][2048] @0 (33,554,432)
    //                    left fp32 [32768][10] @33,554,432 (1,310,720)
    //                    rightT f16 [32768][12] @34,865,152 (786,432)
    //                    Wf f16 [16][64][2][8] @35,651,584 (32,768)   total ~35.7 MB
    _Float16* xT    = (_Float16*)ws;
    float*    left  = (float*)(ws + 33554432);
    _Float16* rightT= (_Float16*)(ws + 34865152);
    _Float16* Wf    = (_Float16*)(ws + 35651584);

    kw_prep<<<4, 256, 0, stream>>>(W1, W2, Wf);
    k01_prep<<<1024, 256, 0, stream>>>(x, Wf, xT, left, rightT);
    k3_attn<<<1024, 256, 0, stream>>>(xT, left, rightT, out);
}

// Round 5
// 230.069 us; speedup vs baseline: 1.1335x; 1.1335x over previous
//
#include <hip/hip_runtime.h>
#include <cstdint>
#include <cstddef>

// Low-rank bilinear attention, MI355X/gfx950.
// out = softmax((x@W1)(W2@x^T)/sqrt(512)) @ x,  x:[16,2048,512] fp32.
// kw:  W1/W2 -> B-fragment f16 table (W1 pre-scaled by log2e/sqrt(512)).
// k01: read x once -> xT f16 [b][d][c] + left16/rightT16 (stride-16, zero-padded).
// k3:  1-barrier/iter software-pipelined fused kernel: P(k+1) from global-direct
//      fragments + exp -> Ps[buf^1], DMA XTl[buf^1], main-GEMM(k) from [buf].

typedef float    f32x4 __attribute__((ext_vector_type(4)));
typedef _Float16 half8 __attribute__((ext_vector_type(8)));
typedef _Float16 half4 __attribute__((ext_vector_type(4)));
typedef _Float16 half2 __attribute__((ext_vector_type(2)));

#define B_  16
#define A_  2048
#define D_  512
#define KSCALE 0.06375872f   // (1/sqrt(512)) * log2(e)

__device__ inline float fast_exp2(float v) {
#if __has_builtin(__builtin_amdgcn_exp2f)
    return __builtin_amdgcn_exp2f(v);
#else
    return __expf(v * 0.6931471805599453f);
#endif
}

// ---- kw: Wf[kt(16)][lane(64)][2 factors][half8]  (32 KB, L2-resident) ----
__global__ __launch_bounds__(256) void kw_prep(const float* __restrict__ W1,
                                               const float* __restrict__ W2,
                                               _Float16* __restrict__ Wf) {
    int pi = blockIdx.x * 256 + threadIdx.x;   // (kt, lane), 1024 total
    int kt = pi >> 6, lane = pi & 63;
    int quad = lane >> 4, col = lane & 15;
    half8 h1, h2;
#pragma unroll
    for (int j = 0; j < 8; ++j) {
        int d = kt * 32 + quad * 8 + j;
        h1[j] = (col < 10) ? (_Float16)(W1[d * 10 + col] * KSCALE) : (_Float16)0.f;
        h2[j] = (col < 10) ? (_Float16)W2[col * 512 + d] : (_Float16)0.f;  // col<10: W2 has 10 rows
    }
    *(half8*)(Wf + (size_t)pi * 16) = h1;
    *(half8*)(Wf + (size_t)pi * 16 + 8) = h2;
}

// ---------------- k01: transpose + factors, x read once ----------------
__global__ __launch_bounds__(256) void k01_prep(const float* __restrict__ x,
                                                const _Float16* __restrict__ Wf,
                                                _Float16* __restrict__ xT,
                                                _Float16* __restrict__ left16,
                                                _Float16* __restrict__ rightT16) {
    __shared__ float xs[32 * 64];
    int t = threadIdx.x, lane = t & 63, w = t >> 6;
    int quad = lane >> 4, c16 = lane & 15;
    int bid = blockIdx.x;
    int b = bid >> 6, grp = bid & 63;
    int c0 = grp << 5;
    const float* xb = x + ((size_t)b * A_ + c0) * D_;
    int tile = w >> 1, kki = w & 1;
    int ar = tile * 16 + c16;
    f32x4 accA = {0.f, 0.f, 0.f, 0.f}, accB = {0.f, 0.f, 0.f, 0.f};

    for (int dc = 0; dc < 8; ++dc) {
        __syncthreads();
#pragma unroll
        for (int p = 0; p < 2; ++p) {         // load 32c x 64d fp32, XOR swizzle
            int c = p * 16 + (t >> 4), ch = t & 15;
            float4 v = *(const float4*)(xb + (size_t)c * D_ + dc * 64 + ch * 4);
            *(float4*)&xs[c * 64 + ((ch ^ (c & 15)) << 2)] = v;
        }
        __syncthreads();
        {                                     // transpose out: half8 per thread
            int dloc = t >> 2, c8 = (t & 3) << 3;
            int ch = dloc >> 2, e = dloc & 3;
            half8 h;
#pragma unroll
            for (int j = 0; j < 8; ++j) {
                int c = c8 + j;
                h[j] = (_Float16)xs[c * 64 + ((ch ^ (c & 15)) << 2) + e];
            }
            *(half8*)(xT + ((size_t)b * D_ + dc * 64 + dloc) * A_ + c0 + c8) = h;
        }
        {                                     // factor MFMAs
            int kk = kki * 32;
            int ch0 = (kk >> 2) + quad * 2;
            float4 v0 = *(const float4*)&xs[ar * 64 + ((ch0 ^ c16) << 2)];
            float4 v1 = *(const float4*)&xs[ar * 64 + (((ch0 + 1) ^ c16) << 2)];
            half8 af;
            af[0] = (_Float16)v0.x; af[1] = (_Float16)v0.y; af[2] = (_Float16)v0.z; af[3] = (_Float16)v0.w;
            af[4] = (_Float16)v1.x; af[5] = (_Float16)v1.y; af[6] = (_Float16)v1.z; af[7] = (_Float16)v1.w;
            const half8* wf = (const half8*)(Wf + ((size_t)((dc * 2 + kki) * 64 + lane)) * 16);
            half8 b1 = wf[0], b2 = wf[1];
            accA = __builtin_amdgcn_mfma_f32_16x16x32_f16(af, b1, accA, 0, 0, 0);
            accB = __builtin_amdgcn_mfma_f32_16x16x32_f16(af, b2, accB, 0, 0, 0);
        }
    }
    __syncthreads();
    float* red = xs;
    if (kki == 0) {
#pragma unroll
        for (int q = 0; q < 4; ++q) {
            red[tile * 512 + (quad * 4 + q) * 16 + c16] = accA[q];
            red[tile * 512 + 256 + (quad * 4 + q) * 16 + c16] = accB[q];
        }
    }
    __syncthreads();
    if (kki == 1) {
#pragma unroll
        for (int q = 0; q < 4; ++q) {
            float a = accA[q] + red[tile * 512 + (quad * 4 + q) * 16 + c16];
            float bb = accB[q] + red[tile * 512 + 256 + (quad * 4 + q) * 16 + c16];
            size_t grow = (size_t)bid * 32 + tile * 16 + quad * 4 + q;
            left16[grow * 16 + c16] = (_Float16)a;     // cols 10..15 exact 0
            rightT16[grow * 16 + c16] = (_Float16)bb;  // cols 10..15 exact 0
        }
    }
}

// ------------- k3: pipelined fused P-recompute + softmax + (P@x) GEMM -------------
// 128a x 128d, 4 waves (64x64), BK=32, grid 1024 (XCD-swizzled), 1 barrier/iter.
// Body k: DMA XTl[nb], global-frag P(k+1) -> exp -> packed b64 Ps[nb]; main(k) from [cb].
__global__ __launch_bounds__(256, 3) void k3_attn(const _Float16* __restrict__ xT,
                                                  const _Float16* __restrict__ left16,
                                                  const _Float16* __restrict__ rightT16,
                                                  float* __restrict__ out) {
    __shared__ _Float16 XTl[2][128 * 32];  // [buf][d-local][c-chunk swizzled], rows 64B
    __shared__ _Float16 Ps[2][128 * 40];   // [buf][a-local][c], stride 40 halfs
    __shared__ float rowsum[128];
    int t = threadIdx.x, lane = t & 63, w = t >> 6;
    int quad = lane >> 4, c16 = lane & 15;
    int bid = blockIdx.x;
    int combo = (bid & 7) | (((bid >> 7) & 7) << 3);  // (b,nb) pinned per XCD
    int at = (bid >> 3) & 15;
    int b = combo >> 2, nb = combo & 3;
    int a0 = at << 7, n0 = nb << 7;
    int waveM = w & 1, waveN = w >> 1;

    // P fragments: lf8 = left B-operand (n=a=c16, k=r=quad*8+j; quads 2,3 = zero pad)
    half8 lf8[2];
#pragma unroll
    for (int i = 0; i < 2; ++i) {
        lf8[i] = (half8)(_Float16)0.f;
        if (quad < 2) {
            int arow = a0 + (2 * w + i) * 16 + c16;
            lf8[i] = *(const half8*)(left16 + ((size_t)(b << 11) + arow) * 16 + quad * 8);
        }
    }

    f32x4 acc[4][4];
#pragma unroll
    for (int mi = 0; mi < 4; ++mi)
#pragma unroll
        for (int ni = 0; ni < 4; ++ni) acc[mi][ni] = (f32x4){0.f, 0.f, 0.f, 0.f};
    float psum[2] = {0.f, 0.f};

    const _Float16* xTb = xT + ((size_t)b * D_ + n0) * A_;
    const _Float16* rTb = rightT16 + (size_t)(b << 11) * 16;

    int nloc0 = w * 32 + (lane >> 2);
    int kq = lane & 3;

    // ---- helpers as lambdas ----
    auto dma_tile = [&](int kt, int buf) {
        int c0 = kt << 5;
#pragma unroll
        for (int cc = 0; cc < 2; ++cc) {
            int nl = nloc0 + cc * 16;
            int kqs = kq ^ ((nl >> 1) & 3);
            const _Float16* src = xTb + (size_t)nl * A_ + c0 + kqs * 8;
            _Float16* dst = &XTl[buf][(w * 32 + cc * 16) * 32];
            __builtin_amdgcn_global_load_lds((const __attribute__((address_space(1))) void*)src,
                                             (__attribute__((address_space(3))) void*)dst,
                                             16, 0, 0);
        }
    };
    auto load_bfr = [&](int kt, half8* bfr) {
#pragma unroll
        for (int nh = 0; nh < 2; ++nh) {
            bfr[nh] = (half8)(_Float16)0.f;
            if (quad < 2) {
                int crow = (kt << 5) + nh * 16 + c16;
                bfr[nh] = *(const half8*)(rTb + (size_t)crow * 16 + quad * 8);
            }
        }
    };
    auto p_phase = [&](const half8* bfr, int buf) {
        // S^T MFMA: A=rightT (m=c), B=left (n=a) -> lane holds a=c16, c=quad*4+q
#pragma unroll
        for (int nh = 0; nh < 2; ++nh) {
#pragma unroll
            for (int i = 0; i < 2; ++i) {
                f32x4 z = {0.f, 0.f, 0.f, 0.f};
                f32x4 pc = __builtin_amdgcn_mfma_f32_16x16x32_f16(bfr[nh], lf8[i], z, 0, 0, 0);
                float e0 = fast_exp2(pc[0]), e1 = fast_exp2(pc[1]);
                float e2 = fast_exp2(pc[2]), e3 = fast_exp2(pc[3]);
                psum[i] += (e0 + e1) + (e2 + e3);
                half4 pv;
                pv[0] = (_Float16)e0; pv[1] = (_Float16)e1;
                pv[2] = (_Float16)e2; pv[3] = (_Float16)e3;
                *(half4*)&Ps[buf][((2 * w + i) * 16 + c16) * 40 + nh * 16 + quad * 4] = pv;
            }
        }
    };

    // ---- prologue: fill buffer 0 ----
    {
        half8 bfr0[2];
        dma_tile(0, 0);
        load_bfr(0, bfr0);
        p_phase(bfr0, 0);
    }

    for (int kt = 0; kt < 64; ++kt) {
        __syncthreads();
        int cb = kt & 1, nxt = kt + 1;
        half8 bfr[2];
        if (nxt < 64) {
            dma_tile(nxt, nxt & 1);
            load_bfr(nxt, bfr);
        }
        // main GEMM from buffer cb
        half8 af[4], bf[4];
#pragma unroll
        for (int mi = 0; mi < 4; ++mi)
            af[mi] = *(const half8*)&Ps[cb][(waveM * 64 + mi * 16 + c16) * 40 + quad * 8];
#pragma unroll
        for (int ni = 0; ni < 4; ++ni) {
            int nr = waveN * 64 + ni * 16 + c16;
            bf[ni] = *(const half8*)&XTl[cb][nr * 32 + ((quad ^ ((nr >> 1) & 3)) << 3)];
        }
#pragma unroll
        for (int mi = 0; mi < 4; ++mi)
#pragma unroll
            for (int ni = 0; ni < 4; ++ni)
                acc[mi][ni] = __builtin_amdgcn_mfma_f32_16x16x32_f16(af[mi], bf[ni], acc[mi][ni], 0, 0, 0);
        if (nxt < 64) p_phase(bfr, nxt & 1);
    }

    // softmax denominators: psum holds partial row-sum for a = (2w+i)*16 + c16
#pragma unroll
    for (int i = 0; i < 2; ++i) {
        float s = psum[i];
        s += __shfl_xor(s, 16);
        s += __shfl_xor(s, 32);
        if (quad == 0) rowsum[(2 * w + i) * 16 + c16] = s;
    }
    __syncthreads();

    float* ob = out + ((size_t)b * A_ + a0) * D_ + n0;
#pragma unroll
    for (int mi = 0; mi < 4; ++mi) {
#pragma unroll
        for (int q = 0; q < 4; ++q) {
            int ar = waveM * 64 + mi * 16 + quad * 4 + q;
            float sc = 1.0f / rowsum[ar];
#pragma unroll
            for (int ni = 0; ni < 4; ++ni)
                ob[(size_t)ar * D_ + waveN * 64 + ni * 16 + c16] = acc[mi][ni][q] * sc;
        }
    }
}

extern "C" void kernel_launch(void* const* d_in, const int* in_sizes, int n_in,
                              void* d_out, int out_size, void* d_ws, size_t ws_size,
                              hipStream_t stream) {
    const float* x  = (const float*)d_in[0];
    const float* W1 = (const float*)d_in[1];
    const float* W2 = (const float*)d_in[2];
    float* out = (float*)d_out;
    char* ws = (char*)d_ws;
    // ws: xT f16 [16][512][2048] @0 (33,554,432)
    //     left16 f16 [32768][16] @33,554,432 (1,048,576)
    //     rightT16 f16 [32768][16] @34,603,008 (1,048,576)
    //     Wf f16 @35,651,584 (32,768)   total 35,684,352 (== round-4 proven footprint)
    _Float16* xT      = (_Float16*)ws;
    _Float16* left16  = (_Float16*)(ws + 33554432);
    _Float16* rightT16= (_Float16*)(ws + 34603008);
    _Float16* Wf      = (_Float16*)(ws + 35651584);

    kw_prep<<<4, 256, 0, stream>>>(W1, W2, Wf);
    k01_prep<<<1024, 256, 0, stream>>>(x, Wf, xT, left16, rightT16);
    k3_attn<<<1024, 256, 0, stream>>>(xT, left16, rightT16, out);
}